// Round 1
// baseline (519.786 us; speedup 1.0000x reference)
//
#include <hip/hip_runtime.h>
#include <hip/hip_bf16.h>

// Sizes fixed by the problem
#define B2      2
#define NX      20000
#define F_IN    128
#define NS1     16000
#define ND1     8000
#define E1      100000
#define ND2     4000
#define E2      60000
#define HEADS   12
#define CH      128
#define K1      1536   // HEADS*CH

static __device__ __forceinline__ float lrelu(float x) { return x > 0.f ? x : 0.2f * x; }

// ---------------------------------------------------------------------------
// GEMM1: hs[32000,1536] = gather(x)[32000,128] @ W1[128,1536]   (f32)
// 64x64 tile, K=128 staged once, 256 threads, 4x4 outputs/thread.
// ---------------------------------------------------------------------------
__global__ __launch_bounds__(256) void k_gemm1(const float* __restrict__ x,
                                               const int* __restrict__ n_id,
                                               const float* __restrict__ W,
                                               float* __restrict__ hs)
{
    __shared__ float As[64][132];   // [m][k], pad 132 (stride%32==4 -> conflict-free reads)
    __shared__ float Bs[128][64];   // [k][n]
    const int tid = threadIdx.x;
    const int bx = blockIdx.x;      // N tiles: 24
    const int by = blockIdx.y;      // M tiles: 500

    // Stage A: 64 rows x 128 cols, gathered through n_id
#pragma unroll
    for (int i = 0; i < 8; ++i) {
        int li = tid + 256 * i;          // 0..2047
        int r  = li >> 5;                // row in tile
        int k4 = (li & 31) << 2;         // k offset
        int grow = by * 64 + r;          // 0..31999
        int b = grow >= NS1 ? 1 : 0;
        int node = n_id[grow - b * NS1];
        const float4 v = *reinterpret_cast<const float4*>(
            x + ((size_t)(b * NX + node)) * F_IN + k4);
        *reinterpret_cast<float4*>(&As[r][k4]) = v;
    }
    // Stage B: 128 k x 64 n
#pragma unroll
    for (int i = 0; i < 8; ++i) {
        int li = tid + 256 * i;
        int k  = li >> 4;
        int c4 = (li & 15) << 2;
        const float4 v = *reinterpret_cast<const float4*>(
            W + (size_t)k * K1 + bx * 64 + c4);
        *reinterpret_cast<float4*>(&Bs[k][c4]) = v;
    }
    __syncthreads();

    const int tx = tid & 15, ty = tid >> 4;
    float acc[4][4] = {};
#pragma unroll 8
    for (int k = 0; k < 128; ++k) {
        float a0 = As[ty * 4 + 0][k];
        float a1 = As[ty * 4 + 1][k];
        float a2 = As[ty * 4 + 2][k];
        float a3 = As[ty * 4 + 3][k];
        float4 b4 = *reinterpret_cast<const float4*>(&Bs[k][tx * 4]);
        acc[0][0] += a0 * b4.x; acc[0][1] += a0 * b4.y; acc[0][2] += a0 * b4.z; acc[0][3] += a0 * b4.w;
        acc[1][0] += a1 * b4.x; acc[1][1] += a1 * b4.y; acc[1][2] += a1 * b4.z; acc[1][3] += a1 * b4.w;
        acc[2][0] += a2 * b4.x; acc[2][1] += a2 * b4.y; acc[2][2] += a2 * b4.z; acc[2][3] += a2 * b4.w;
        acc[3][0] += a3 * b4.x; acc[3][1] += a3 * b4.y; acc[3][2] += a3 * b4.z; acc[3][3] += a3 * b4.w;
    }
#pragma unroll
    for (int i = 0; i < 4; ++i) {
        size_t row = (size_t)by * 64 + ty * 4 + i;
        float4 v = make_float4(acc[i][0], acc[i][1], acc[i][2], acc[i][3]);
        *reinterpret_cast<float4*>(hs + row * K1 + bx * 64 + tx * 4) = v;
    }
}

// ---------------------------------------------------------------------------
// Attention scores: out[(b*nper+j)*12+h] = dot(hs[b*NS1+rowsel(j)][h*128:...], att[h])
// One wave per (b,j). idx==nullptr -> rowsel(j)=j (e_s); else rowsel=idx[j] (e_d).
// ---------------------------------------------------------------------------
__global__ __launch_bounds__(256) void k_attn(const float* __restrict__ hs,
                                              const int* __restrict__ idx,
                                              int nper,
                                              const float* __restrict__ att,
                                              float* __restrict__ out)
{
    int wave = (blockIdx.x * 256 + threadIdx.x) >> 6;
    int lane = threadIdx.x & 63;
    int total = 2 * nper;
    if (wave >= total) return;
    int b = wave / nper;
    int j = wave - b * nper;
    int srcrow = idx ? idx[j] : j;
    const float* row = hs + ((size_t)(b * NS1 + srcrow)) * K1;
#pragma unroll
    for (int h = 0; h < HEADS; ++h) {
        float2 v = *reinterpret_cast<const float2*>(row + h * CH + lane * 2);
        float2 a = *reinterpret_cast<const float2*>(att + h * CH + lane * 2);
        float p = v.x * a.x + v.y * a.y;
#pragma unroll
        for (int o = 32; o > 0; o >>= 1) p += __shfl_xor(p, o);
        if (lane == 0) out[(size_t)wave * HEADS + h] = p;
    }
}

// ---------------------------------------------------------------------------
// CSR build: count -> exclusive scan (single block) -> scatter
// ---------------------------------------------------------------------------
__global__ void k_count(const int* __restrict__ dst, int E, int* __restrict__ deg)
{
    int e = blockIdx.x * 256 + threadIdx.x;
    if (e < E) atomicAdd(&deg[dst[e]], 1);
}

__global__ __launch_bounds__(1024) void k_scan(const int* __restrict__ deg, int n,
                                               int* __restrict__ off, int* __restrict__ cursor)
{
    __shared__ int sm[1024];
    __shared__ int carry;
    int tid = threadIdx.x;
    if (tid == 0) { carry = 0; off[0] = 0; }
    __syncthreads();
    for (int base = 0; base < n; base += 1024) {
        int i = base + tid;
        int v = (i < n) ? deg[i] : 0;
        sm[tid] = v;
        __syncthreads();
        for (int o = 1; o < 1024; o <<= 1) {
            int t = (tid >= o) ? sm[tid - o] : 0;
            __syncthreads();
            sm[tid] += t;
            __syncthreads();
        }
        if (i < n) {
            off[i + 1] = carry + sm[tid];
            cursor[i]  = carry + sm[tid] - v;
        }
        int tot = sm[1023];
        __syncthreads();
        if (tid == 0) carry += tot;
        __syncthreads();
    }
}

__global__ void k_scatter(const int* __restrict__ dst, int E,
                          int* __restrict__ cursor, int* __restrict__ eid)
{
    int e = blockIdx.x * 256 + threadIdx.x;
    if (e < E) {
        int p = atomicAdd(&cursor[dst[e]], 1);
        eid[p] = e;
    }
}

// ---------------------------------------------------------------------------
// Layer-1 aggregate: per (dst i, batch b) block. Online softmax over edge
// chunks; register accumulation of 1536 channels (6/thread); epilogue fuses
// +bias1, relu, dot(W2) -> s2[b*ND1+i]. Layer-1 output never materialized.
// ---------------------------------------------------------------------------
#define CHUNK 64
__global__ __launch_bounds__(256) void k_agg1(const float* __restrict__ hs,
                                              const float* __restrict__ e_s,
                                              const float* __restrict__ e_d,
                                              const int* __restrict__ off,
                                              const int* __restrict__ eid,
                                              const int* __restrict__ src1,
                                              const float* __restrict__ bias1,
                                              const float* __restrict__ W2,
                                              float* __restrict__ s2)
{
    const int i = blockIdx.x;   // dst node
    const int b = blockIdx.y;   // batch
    const int tid = threadIdx.x;

    __shared__ float a_ch[CHUNK][HEADS];
    __shared__ int   src_ch[CHUNK];
    __shared__ float m_sh[HEADS], den_sh[HEADS], fac_sh[HEADS], ed_sh[HEADS];
    __shared__ float red[256];

    int beg = off[i], end = off[i + 1];
    int deg = end - beg;

    if (tid < HEADS) {
        m_sh[tid] = -INFINITY;
        den_sh[tid] = 0.f;
        ed_sh[tid] = e_d[((size_t)b * ND1 + i) * HEADS + tid];
    }
    float acc[6] = {0.f, 0.f, 0.f, 0.f, 0.f, 0.f};
    __syncthreads();

    for (int cbeg = 0; cbeg < deg; cbeg += CHUNK) {
        int cnt = min(CHUNK, deg - cbeg);
        if (tid < cnt) src_ch[tid] = src1[eid[beg + cbeg + tid]];
        __syncthreads();
        for (int idx = tid; idx < cnt * HEADS; idx += 256) {
            int e = idx / HEADS, h = idx - e * HEADS;
            float al = e_s[((size_t)b * NS1 + src_ch[e]) * HEADS + h] + ed_sh[h];
            a_ch[e][h] = lrelu(al);
        }
        __syncthreads();
        if (tid < HEADS) {
            int h = tid;
            float m = m_sh[h];
            float nm = m;
            for (int e = 0; e < cnt; ++e) nm = fmaxf(nm, a_ch[e][h]);
            float fac = (m == -INFINITY) ? 0.f : __expf(m - nm);
            float d = den_sh[h] * fac;
            for (int e = 0; e < cnt; ++e) {
                float w = __expf(a_ch[e][h] - nm);
                a_ch[e][h] = w;
                d += w;
            }
            m_sh[h] = nm; den_sh[h] = d; fac_sh[h] = fac;
        }
        __syncthreads();
#pragma unroll
        for (int q = 0; q < 6; ++q) {
            int k = tid + 256 * q;
            int h = k >> 7;
            float a = acc[q] * fac_sh[h];
            for (int e = 0; e < cnt; ++e) {
                a += a_ch[e][h] * hs[((size_t)b * NS1 + src_ch[e]) * K1 + k];
            }
            acc[q] = a;
        }
        __syncthreads();
    }

    // epilogue: /den, +bias, relu, dot W2
    float part = 0.f;
#pragma unroll
    for (int q = 0; q < 6; ++q) {
        int k = tid + 256 * q;
        int h = k >> 7;
        float o = acc[q] / (den_sh[h] + 1e-16f);
        float v = o + bias1[k];
        v = v > 0.f ? v : 0.f;
        part += v * W2[k];
    }
    red[tid] = part;
    __syncthreads();
    for (int s = 128; s > 0; s >>= 1) {
        if (tid < s) red[tid] += red[tid + s];
        __syncthreads();
    }
    if (tid == 0) s2[(size_t)b * ND1 + i] = red[0];
}

// ---------------------------------------------------------------------------
// Layer-2 (heads=1, ch=1): one thread per (dst j, batch b).
// ---------------------------------------------------------------------------
__global__ void k_agg2(const float* __restrict__ s2,
                       const int* __restrict__ off,
                       const int* __restrict__ eid,
                       const int* __restrict__ src2,
                       const int* __restrict__ res2,
                       const float* __restrict__ asrc,
                       const float* __restrict__ adst,
                       const float* __restrict__ bias2,
                       float* __restrict__ out)
{
    int t = blockIdx.x * 256 + threadIdx.x;
    if (t >= 2 * ND2) return;
    int b = t / ND2, j = t - b * ND2;
    float a_s = asrc[0], a_d = adst[0];
    float ed = s2[(size_t)b * ND1 + res2[j]] * a_d;
    int beg = off[j], end = off[j + 1];
    float m = -INFINITY;
    for (int p = beg; p < end; ++p) {
        int s = src2[eid[p]];
        m = fmaxf(m, lrelu(s2[b * ND1 + s] * a_s + ed));
    }
    float den = 0.f, num = 0.f;
    for (int p = beg; p < end; ++p) {
        int s = src2[eid[p]];
        float v = s2[b * ND1 + s];
        float al = lrelu(v * a_s + ed);
        float w = __expf(al - m);
        den += w;
        num += w * v;
    }
    float o = (end > beg) ? num / (den + 1e-16f) : 0.f;
    out[(size_t)b * ND2 + j] = o + bias2[0];
}

// ---------------------------------------------------------------------------
extern "C" void kernel_launch(void* const* d_in, const int* in_sizes, int n_in,
                              void* d_out, int out_size, void* d_ws, size_t ws_size,
                              hipStream_t stream)
{
    const float* x        = (const float*)d_in[0];
    const int* n_id1      = (const int*)d_in[1];
    const int* res_n_id1  = (const int*)d_in[2];
    const int* src1       = (const int*)d_in[3];
    const int* dst1       = (const int*)d_in[4];
    const int* res_n_id2  = (const int*)d_in[5];
    const int* src2       = (const int*)d_in[6];
    const int* dst2       = (const int*)d_in[7];
    const float* W1       = (const float*)d_in[8];
    const float* att_src1 = (const float*)d_in[9];
    const float* att_dst1 = (const float*)d_in[10];
    const float* bias1    = (const float*)d_in[11];
    const float* W2       = (const float*)d_in[12];
    const float* att_src2 = (const float*)d_in[13];
    const float* att_dst2 = (const float*)d_in[14];
    const float* bias2    = (const float*)d_in[15];

    // workspace layout (floats/ints, all 16B aligned)
    float* hs  = (float*)d_ws;                     // 2*16000*1536 = 49,152,000
    float* e_s = hs + (size_t)2 * NS1 * K1;        // 2*16000*12   =    384,000
    float* e_d = e_s + (size_t)2 * NS1 * HEADS;    // 2*8000*12    =    192,000
    float* s2  = e_d + (size_t)2 * ND1 * HEADS;    // 2*8000       =     16,000
    int* deg1  = (int*)(s2 + (size_t)2 * ND1);     // 8000
    int* deg2  = deg1 + ND1;                       // 4000
    int* off1  = deg2 + ND2;                       // 8001
    int* off2  = off1 + (ND1 + 1);                 // 4001
    int* cur1  = off2 + (ND2 + 1);                 // 8000
    int* cur2  = cur1 + ND1;                       // 4000
    int* eid1  = cur2 + ND2;                       // 100000
    int* eid2  = eid1 + E1;                        // 60000

    // zero the degree counters every call (atomics accumulate otherwise)
    hipMemsetAsync(deg1, 0, (ND1 + ND2) * sizeof(int), stream);

    // 1) projection GEMM
    k_gemm1<<<dim3(K1 / 64, (2 * NS1) / 64), 256, 0, stream>>>(x, n_id1, W1, hs);

    // 2) attention scores
    k_attn<<<(2 * NS1) / 4, 256, 0, stream>>>(hs, nullptr, NS1, att_src1, e_s);
    k_attn<<<(2 * ND1) / 4, 256, 0, stream>>>(hs, res_n_id1, ND1, att_dst1, e_d);

    // 3) CSR for layer 1 and layer 2
    k_count<<<(E1 + 255) / 256, 256, 0, stream>>>(dst1, E1, deg1);
    k_scan<<<1, 1024, 0, stream>>>(deg1, ND1, off1, cur1);
    k_scatter<<<(E1 + 255) / 256, 256, 0, stream>>>(dst1, E1, cur1, eid1);

    k_count<<<(E2 + 255) / 256, 256, 0, stream>>>(dst2, E2, deg2);
    k_scan<<<1, 1024, 0, stream>>>(deg2, ND2, off2, cur2);
    k_scatter<<<(E2 + 255) / 256, 256, 0, stream>>>(dst2, E2, cur2, eid2);

    // 4) layer-1 softmax-aggregate fused with bias+relu+dot(W2) -> s2
    k_agg1<<<dim3(ND1, B2), 256, 0, stream>>>(hs, e_s, e_d, off1, eid1, src1,
                                              bias1, W2, s2);

    // 5) layer-2 (1 head, 1 channel)
    k_agg2<<<(2 * ND2 + 255) / 256, 256, 0, stream>>>(s2, off2, eid2, src2,
                                                      res_n_id2, att_src2,
                                                      att_dst2, bias2,
                                                      (float*)d_out);
}

// Round 2
// 338.370 us; speedup vs baseline: 1.5361x; 1.5361x over previous
//
#include <hip/hip_runtime.h>
#include <hip/hip_bf16.h>

// Sizes fixed by the problem
#define B2      2
#define NX      20000
#define F_IN    128
#define NS1     16000
#define ND1     8000
#define E1      100000
#define ND2     4000
#define E2      60000
#define HEADS   12
#define CH      128
#define K1      1536   // HEADS*CH

typedef __bf16 bf16x8 __attribute__((ext_vector_type(8)));
typedef float  f32x4  __attribute__((ext_vector_type(4)));

static __device__ __forceinline__ float lrelu(float x) { return x > 0.f ? x : 0.2f * x; }

// f32 -> bf16 (RNE) as ushort bits
static __device__ __forceinline__ unsigned short f2bf(float f) {
    union { float f; unsigned u; } v; v.f = f;
    unsigned r = v.u + 0x7fffu + ((v.u >> 16) & 1u);
    return (unsigned short)(r >> 16);
}
// bf16 bits -> f32
static __device__ __forceinline__ float bf2f(unsigned short h) {
    union { unsigned u; float f; } v; v.u = ((unsigned)h) << 16;
    return v.f;
}

// ---------------------------------------------------------------------------
// Pre-pass A: xg[32000][128] bf16 = gather(x via n_id1), per batch.
// ---------------------------------------------------------------------------
__global__ __launch_bounds__(256) void k_convA(const float* __restrict__ x,
                                               const int* __restrict__ n_id,
                                               unsigned short* __restrict__ xg)
{
    int t = blockIdx.x * 256 + threadIdx.x;          // 0 .. 1,023,999 (float4 units)
    if (t >= 2 * NS1 * (F_IN / 4)) return;
    int row = t >> 5;                                // 0..31999
    int c4 = (t & 31) << 2;
    int b = row >= NS1 ? 1 : 0;
    int node = n_id[row - b * NS1];
    const float4 v = *reinterpret_cast<const float4*>(
        x + ((size_t)(b * NX + node)) * F_IN + c4);
    ushort4 o;
    o.x = f2bf(v.x); o.y = f2bf(v.y); o.z = f2bf(v.z); o.w = f2bf(v.w);
    *reinterpret_cast<ushort4*>(xg + (size_t)row * F_IN + c4) = o;
}

// ---------------------------------------------------------------------------
// Pre-pass B: W1T[1536][128] bf16 = transpose(W1[128][1536]) in bf16.
// ---------------------------------------------------------------------------
__global__ __launch_bounds__(256) void k_convB(const float* __restrict__ W,
                                               unsigned short* __restrict__ WT)
{
    int t = blockIdx.x * 256 + threadIdx.x;          // 0 .. 196607
    if (t >= F_IN * K1) return;
    int k = t / K1;
    int n = t - k * K1;
    WT[(size_t)n * F_IN + k] = f2bf(W[t]);           // coalesced read, scattered 2B write (small)
}

// ---------------------------------------------------------------------------
// MFMA GEMM: hs16[32000,1536](bf16) = xg[32000,128] @ W1T^T
// 64x64 tile per block, 4 waves, no LDS: fragments loaded straight from
// L2-resident bf16 buffers as contiguous 16B chunks.
// Fragment layout (verified m89/m92): A elem j of lane l = A[l&15][(l>>4)*8+j],
// B elem j = B[(l>>4)*8+j][l&15], D reg r = D[(l>>4)*4+r][l&15].
// ---------------------------------------------------------------------------
__global__ __launch_bounds__(256) void k_gemm1b(const unsigned short* __restrict__ xg,
                                                const unsigned short* __restrict__ WT,
                                                unsigned short* __restrict__ hs)
{
    const int tid  = threadIdx.x;
    const int wave = tid >> 6;
    const int lane = tid & 63;
    const int l15  = lane & 15;
    const int l4   = lane >> 4;

    const int m0 = blockIdx.y * 64 + wave * 16 + l15;   // row this lane owns for A
    const int n0 = blockIdx.x * 64;                      // col tile base

    const unsigned short* Ap = xg + (size_t)m0 * F_IN + l4 * 8;

    f32x4 acc[4] = {f32x4{0,0,0,0}, f32x4{0,0,0,0}, f32x4{0,0,0,0}, f32x4{0,0,0,0}};

#pragma unroll
    for (int kk = 0; kk < 4; ++kk) {
        bf16x8 a = *reinterpret_cast<const bf16x8*>(Ap + kk * 32);
#pragma unroll
        for (int c = 0; c < 4; ++c) {
            const unsigned short* Bp =
                WT + (size_t)(n0 + c * 16 + l15) * F_IN + l4 * 8 + kk * 32;
            bf16x8 b = *reinterpret_cast<const bf16x8*>(Bp);
            acc[c] = __builtin_amdgcn_mfma_f32_16x16x32_bf16(a, b, acc[c], 0, 0, 0);
        }
    }

    const int rbase = blockIdx.y * 64 + wave * 16 + l4 * 4;
#pragma unroll
    for (int c = 0; c < 4; ++c) {
        int col = n0 + c * 16 + l15;
#pragma unroll
        for (int r = 0; r < 4; ++r) {
            hs[(size_t)(rbase + r) * K1 + col] = f2bf(acc[c][r]);
        }
    }
}

// ---------------------------------------------------------------------------
// Attention scores from bf16 hs. One wave per (b,j); 12 heads.
// ---------------------------------------------------------------------------
__global__ __launch_bounds__(256) void k_attn(const unsigned short* __restrict__ hs,
                                              const int* __restrict__ idx,
                                              int nper,
                                              const float* __restrict__ att,
                                              float* __restrict__ out)
{
    int wave = (blockIdx.x * 256 + threadIdx.x) >> 6;
    int lane = threadIdx.x & 63;
    int total = 2 * nper;
    if (wave >= total) return;
    int b = wave / nper;
    int j = wave - b * nper;
    int srcrow = idx ? idx[j] : j;
    const unsigned* row32 = reinterpret_cast<const unsigned*>(
        hs + ((size_t)(b * NS1 + srcrow)) * K1);
#pragma unroll
    for (int h = 0; h < HEADS; ++h) {
        unsigned u = row32[h * 64 + lane];           // 2 bf16
        float lo = bf2f((unsigned short)(u & 0xffff));
        float hi = bf2f((unsigned short)(u >> 16));
        float2 a = *reinterpret_cast<const float2*>(att + h * CH + lane * 2);
        float p = lo * a.x + hi * a.y;
#pragma unroll
        for (int o = 32; o > 0; o >>= 1) p += __shfl_xor(p, o);
        if (lane == 0) out[(size_t)wave * HEADS + h] = p;
    }
}

// ---------------------------------------------------------------------------
// CSR build: count -> exclusive scan (single block) -> scatter
// ---------------------------------------------------------------------------
__global__ void k_count(const int* __restrict__ dst, int E, int* __restrict__ deg)
{
    int e = blockIdx.x * 256 + threadIdx.x;
    if (e < E) atomicAdd(&deg[dst[e]], 1);
}

__global__ __launch_bounds__(1024) void k_scan(const int* __restrict__ deg, int n,
                                               int* __restrict__ off, int* __restrict__ cursor)
{
    __shared__ int sm[1024];
    __shared__ int carry;
    int tid = threadIdx.x;
    if (tid == 0) { carry = 0; off[0] = 0; }
    __syncthreads();
    for (int base = 0; base < n; base += 1024) {
        int i = base + tid;
        int v = (i < n) ? deg[i] : 0;
        sm[tid] = v;
        __syncthreads();
        for (int o = 1; o < 1024; o <<= 1) {
            int t = (tid >= o) ? sm[tid - o] : 0;
            __syncthreads();
            sm[tid] += t;
            __syncthreads();
        }
        if (i < n) {
            off[i + 1] = carry + sm[tid];
            cursor[i]  = carry + sm[tid] - v;
        }
        int tot = sm[1023];
        __syncthreads();
        if (tid == 0) carry += tot;
        __syncthreads();
    }
}

__global__ void k_scatter(const int* __restrict__ dst, int E,
                          int* __restrict__ cursor, int* __restrict__ eid)
{
    int e = blockIdx.x * 256 + threadIdx.x;
    if (e < E) {
        int p = atomicAdd(&cursor[dst[e]], 1);
        eid[p] = e;
    }
}

// ---------------------------------------------------------------------------
// Layer-1 aggregate (bf16 hs): per (dst i, batch b) block. Online softmax over
// edge chunks; register accumulation of 1536 channels (6/thread); epilogue
// fuses +bias1, relu, dot(W2) -> s2[b*ND1+i].
// ---------------------------------------------------------------------------
#define CHUNK 64
__global__ __launch_bounds__(256) void k_agg1(const unsigned short* __restrict__ hs,
                                              const float* __restrict__ e_s,
                                              const float* __restrict__ e_d,
                                              const int* __restrict__ off,
                                              const int* __restrict__ eid,
                                              const int* __restrict__ src1,
                                              const float* __restrict__ bias1,
                                              const float* __restrict__ W2,
                                              float* __restrict__ s2)
{
    const int i = blockIdx.x;   // dst node
    const int b = blockIdx.y;   // batch
    const int tid = threadIdx.x;

    __shared__ float a_ch[CHUNK][HEADS];
    __shared__ int   src_ch[CHUNK];
    __shared__ float m_sh[HEADS], den_sh[HEADS], fac_sh[HEADS], ed_sh[HEADS];
    __shared__ float red[256];

    int beg = off[i], end = off[i + 1];
    int deg = end - beg;

    if (tid < HEADS) {
        m_sh[tid] = -INFINITY;
        den_sh[tid] = 0.f;
        ed_sh[tid] = e_d[((size_t)b * ND1 + i) * HEADS + tid];
    }
    float acc[6] = {0.f, 0.f, 0.f, 0.f, 0.f, 0.f};
    int hq[6];
#pragma unroll
    for (int q = 0; q < 6; ++q) hq[q] = 2 * q + (tid >> 7);
    __syncthreads();

    for (int cbeg = 0; cbeg < deg; cbeg += CHUNK) {
        int cnt = min(CHUNK, deg - cbeg);
        if (tid < cnt) src_ch[tid] = src1[eid[beg + cbeg + tid]];
        __syncthreads();
        for (int idx = tid; idx < cnt * HEADS; idx += 256) {
            int e = idx / HEADS, h = idx - e * HEADS;
            float al = e_s[((size_t)b * NS1 + src_ch[e]) * HEADS + h] + ed_sh[h];
            a_ch[e][h] = lrelu(al);
        }
        __syncthreads();
        if (tid < HEADS) {
            int h = tid;
            float m = m_sh[h];
            float nm = m;
            for (int e = 0; e < cnt; ++e) nm = fmaxf(nm, a_ch[e][h]);
            float fac = (m == -INFINITY) ? 0.f : __expf(m - nm);
            float d = den_sh[h] * fac;
            for (int e = 0; e < cnt; ++e) {
                float w = __expf(a_ch[e][h] - nm);
                a_ch[e][h] = w;
                d += w;
            }
            m_sh[h] = nm; den_sh[h] = d; fac_sh[h] = fac;
        }
        __syncthreads();
#pragma unroll
        for (int q = 0; q < 6; ++q) acc[q] *= fac_sh[hq[q]];
        for (int e = 0; e < cnt; ++e) {
            const unsigned short* row = hs + ((size_t)(b * NS1 + src_ch[e])) * K1 + tid;
#pragma unroll
            for (int q = 0; q < 6; ++q) {
                acc[q] += a_ch[e][hq[q]] * bf2f(row[256 * q]);
            }
        }
        __syncthreads();
    }

    // epilogue: /den, +bias, relu, dot W2
    float part = 0.f;
#pragma unroll
    for (int q = 0; q < 6; ++q) {
        int k = tid + 256 * q;
        float o = acc[q] / (den_sh[hq[q]] + 1e-16f);
        float v = o + bias1[k];
        v = v > 0.f ? v : 0.f;
        part += v * W2[k];
    }
    red[tid] = part;
    __syncthreads();
    for (int s = 128; s > 0; s >>= 1) {
        if (tid < s) red[tid] += red[tid + s];
        __syncthreads();
    }
    if (tid == 0) s2[(size_t)b * ND1 + i] = red[0];
}

// ---------------------------------------------------------------------------
// Layer-2 (heads=1, ch=1): one thread per (dst j, batch b).
// ---------------------------------------------------------------------------
__global__ void k_agg2(const float* __restrict__ s2,
                       const int* __restrict__ off,
                       const int* __restrict__ eid,
                       const int* __restrict__ src2,
                       const int* __restrict__ res2,
                       const float* __restrict__ asrc,
                       const float* __restrict__ adst,
                       const float* __restrict__ bias2,
                       float* __restrict__ out)
{
    int t = blockIdx.x * 256 + threadIdx.x;
    if (t >= 2 * ND2) return;
    int b = t / ND2, j = t - b * ND2;
    float a_s = asrc[0], a_d = adst[0];
    float ed = s2[(size_t)b * ND1 + res2[j]] * a_d;
    int beg = off[j], end = off[j + 1];
    float m = -INFINITY;
    for (int p = beg; p < end; ++p) {
        int s = src2[eid[p]];
        m = fmaxf(m, lrelu(s2[b * ND1 + s] * a_s + ed));
    }
    float den = 0.f, num = 0.f;
    for (int p = beg; p < end; ++p) {
        int s = src2[eid[p]];
        float v = s2[b * ND1 + s];
        float al = lrelu(v * a_s + ed);
        float w = __expf(al - m);
        den += w;
        num += w * v;
    }
    float o = (end > beg) ? num / (den + 1e-16f) : 0.f;
    out[(size_t)b * ND2 + j] = o + bias2[0];
}

// ---------------------------------------------------------------------------
extern "C" void kernel_launch(void* const* d_in, const int* in_sizes, int n_in,
                              void* d_out, int out_size, void* d_ws, size_t ws_size,
                              hipStream_t stream)
{
    const float* x        = (const float*)d_in[0];
    const int* n_id1      = (const int*)d_in[1];
    const int* res_n_id1  = (const int*)d_in[2];
    const int* src1       = (const int*)d_in[3];
    const int* dst1       = (const int*)d_in[4];
    const int* res_n_id2  = (const int*)d_in[5];
    const int* src2       = (const int*)d_in[6];
    const int* dst2       = (const int*)d_in[7];
    const float* W1       = (const float*)d_in[8];
    const float* att_src1 = (const float*)d_in[9];
    const float* att_dst1 = (const float*)d_in[10];
    const float* bias1    = (const float*)d_in[11];
    const float* W2       = (const float*)d_in[12];
    const float* att_src2 = (const float*)d_in[13];
    const float* att_dst2 = (const float*)d_in[14];
    const float* bias2    = (const float*)d_in[15];

    // workspace layout (16B aligned)
    unsigned short* hs16 = (unsigned short*)d_ws;            // 49,152,000 ushort
    unsigned short* xg   = hs16 + (size_t)2 * NS1 * K1;      //  4,096,000 ushort
    unsigned short* W1T  = xg + (size_t)2 * NS1 * F_IN;      //    196,608 ushort
    float* e_s = (float*)(W1T + (size_t)K1 * F_IN);          //    384,000 f32
    float* e_d = e_s + (size_t)2 * NS1 * HEADS;              //    192,000 f32
    float* s2  = e_d + (size_t)2 * ND1 * HEADS;              //     16,000 f32
    int* deg1  = (int*)(s2 + (size_t)2 * ND1);               // 8000
    int* deg2  = deg1 + ND1;                                 // 4000
    int* off1  = deg2 + ND2;                                 // 8001
    int* off2  = off1 + (ND1 + 1);                           // 4001
    int* cur1  = off2 + (ND2 + 1);                           // 8000
    int* cur2  = cur1 + ND1;                                 // 4000
    int* eid1  = cur2 + ND2;                                 // 100000
    int* eid2  = eid1 + E1;                                  // 60000

    // zero the degree counters every call (atomics accumulate otherwise)
    hipMemsetAsync(deg1, 0, (ND1 + ND2) * sizeof(int), stream);

    // 0) pre-convert to bf16
    k_convA<<<(2 * NS1 * (F_IN / 4) + 255) / 256, 256, 0, stream>>>(x, n_id1, xg);
    k_convB<<<(F_IN * K1 + 255) / 256, 256, 0, stream>>>(W1, W1T);

    // 1) projection GEMM (bf16 MFMA, no LDS)
    k_gemm1b<<<dim3(K1 / 64, (2 * NS1) / 64), 256, 0, stream>>>(xg, W1T, hs16);

    // 2) attention scores
    k_attn<<<(2 * NS1) / 4, 256, 0, stream>>>(hs16, nullptr, NS1, att_src1, e_s);
    k_attn<<<(2 * ND1) / 4, 256, 0, stream>>>(hs16, res_n_id1, ND1, att_dst1, e_d);

    // 3) CSR for layer 1 and layer 2
    k_count<<<(E1 + 255) / 256, 256, 0, stream>>>(dst1, E1, deg1);
    k_scan<<<1, 1024, 0, stream>>>(deg1, ND1, off1, cur1);
    k_scatter<<<(E1 + 255) / 256, 256, 0, stream>>>(dst1, E1, cur1, eid1);

    k_count<<<(E2 + 255) / 256, 256, 0, stream>>>(dst2, E2, deg2);
    k_scan<<<1, 1024, 0, stream>>>(deg2, ND2, off2, cur2);
    k_scatter<<<(E2 + 255) / 256, 256, 0, stream>>>(dst2, E2, cur2, eid2);

    // 4) layer-1 softmax-aggregate fused with bias+relu+dot(W2) -> s2
    k_agg1<<<dim3(ND1, B2), 256, 0, stream>>>(hs16, e_s, e_d, off1, eid1, src1,
                                              bias1, W2, s2);

    // 5) layer-2 (1 head, 1 channel)
    k_agg2<<<(2 * ND2 + 255) / 256, 256, 0, stream>>>(s2, off2, eid2, src2,
                                                      res_n_id2, att_src2,
                                                      att_dst2, bias2,
                                                      (float*)d_out);
}

// Round 3
// 201.458 us; speedup vs baseline: 2.5801x; 1.6796x over previous
//
#include <hip/hip_runtime.h>
#include <hip/hip_bf16.h>

// Sizes fixed by the problem
#define B2      2
#define NX      20000
#define F_IN    128
#define NS1     16000
#define ND1     8000
#define E1      100000
#define ND2     4000
#define E2      60000
#define HEADS   12
#define CH      128
#define K1      1536   // HEADS*CH

typedef __bf16 bf16x8 __attribute__((ext_vector_type(8)));
typedef float  f32x4  __attribute__((ext_vector_type(4)));

static __device__ __forceinline__ float lrelu(float x) { return x > 0.f ? x : 0.2f * x; }

static __device__ __forceinline__ unsigned short f2bf(float f) {
    union { float f; unsigned u; } v; v.f = f;
    unsigned r = v.u + 0x7fffu + ((v.u >> 16) & 1u);
    return (unsigned short)(r >> 16);
}
static __device__ __forceinline__ float bf2f(unsigned short h) {
    union { unsigned u; float f; } v; v.u = ((unsigned)h) << 16;
    return v.f;
}

// ---------------------------------------------------------------------------
// xg[32000][128] bf16 = gather(x via n_id1), both batches.
// ---------------------------------------------------------------------------
__global__ __launch_bounds__(256) void k_convA(const float* __restrict__ x,
                                               const int* __restrict__ n_id,
                                               unsigned short* __restrict__ xg)
{
    int t = blockIdx.x * 256 + threadIdx.x;          // float4 units
    if (t >= 2 * NS1 * (F_IN / 4)) return;
    int row = t >> 5;
    int c4 = (t & 31) << 2;
    int b = row >= NS1 ? 1 : 0;
    int node = n_id[row - b * NS1];
    const float4 v = *reinterpret_cast<const float4*>(
        x + ((size_t)(b * NX + node)) * F_IN + c4);
    ushort4 o;
    o.x = f2bf(v.x); o.y = f2bf(v.y); o.z = f2bf(v.z); o.w = f2bf(v.w);
    *reinterpret_cast<ushort4*>(xg + (size_t)row * F_IN + c4) = o;
}

// ---------------------------------------------------------------------------
// W1T[1536][128] bf16 = transpose(W1[128][1536]).
// ---------------------------------------------------------------------------
__global__ __launch_bounds__(256) void k_convB(const float* __restrict__ W,
                                               unsigned short* __restrict__ WT)
{
    int t = blockIdx.x * 256 + threadIdx.x;
    if (t >= F_IN * K1) return;
    int k = t / K1;
    int n = t - k * K1;
    WT[(size_t)n * F_IN + k] = f2bf(W[t]);
}

// ---------------------------------------------------------------------------
// wswd[32][128] bf16: n<12 -> ws[h]=W1_h@a_src[h]; 12<=n<24 -> wd; else 0.
// ---------------------------------------------------------------------------
__global__ __launch_bounds__(256) void k_ws(const float* __restrict__ W,
                                            const float* __restrict__ asrc,
                                            const float* __restrict__ adst,
                                            unsigned short* __restrict__ wswd)
{
    int t = blockIdx.x * 256 + threadIdx.x;          // 0..4095
    if (t >= 32 * F_IN) return;
    int n = t >> 7;
    int c = t & 127;
    float acc = 0.f;
    if (n < 24) {
        int h = n < 12 ? n : n - 12;
        const float* att = (n < 12 ? asrc : adst) + h * CH;
        const float* wr = W + (size_t)c * K1 + h * CH;
        for (int j = 0; j < CH; ++j) acc += wr[j] * att[j];
    }
    wswd[(size_t)n * F_IN + c] = f2bf(acc);
}

// ---------------------------------------------------------------------------
// Scores: [32000,128] @ wswd^T -> es[row][12], ed[row][12].  MFMA, 1 wave per
// 16 rows. Fragment layout per verified m89/m92 mapping.
// ---------------------------------------------------------------------------
__global__ __launch_bounds__(256) void k_escore(const unsigned short* __restrict__ xg,
                                                const unsigned short* __restrict__ wswd,
                                                float* __restrict__ es,
                                                float* __restrict__ ed)
{
    const int tid = threadIdx.x;
    const int wave = tid >> 6, lane = tid & 63;
    const int l15 = lane & 15, l4 = lane >> 4;
    const int rt = blockIdx.x * 4 + wave;            // 0..1999
    const int row0 = rt * 16;
    const unsigned short* Ap = xg + (size_t)(row0 + l15) * F_IN + l4 * 8;

    f32x4 acc[2] = {f32x4{0,0,0,0}, f32x4{0,0,0,0}};
#pragma unroll
    for (int kk = 0; kk < 4; ++kk) {
        bf16x8 a = *reinterpret_cast<const bf16x8*>(Ap + kk * 32);
#pragma unroll
        for (int c = 0; c < 2; ++c) {
            bf16x8 b = *reinterpret_cast<const bf16x8*>(
                wswd + (size_t)(c * 16 + l15) * F_IN + kk * 32 + l4 * 8);
            acc[c] = __builtin_amdgcn_mfma_f32_16x16x32_bf16(a, b, acc[c], 0, 0, 0);
        }
    }
#pragma unroll
    for (int c = 0; c < 2; ++c) {
        int col = c * 16 + l15;
#pragma unroll
        for (int r = 0; r < 4; ++r) {
            int row = row0 + l4 * 4 + r;
            float v = acc[c][r];
            if (col < 12)       es[(size_t)row * HEADS + col] = v;
            else if (col < 24)  ed[(size_t)row * HEADS + (col - 12)] = v;
        }
    }
}

// ---------------------------------------------------------------------------
// CSR build: count -> single-block shfl scan -> scatter
// ---------------------------------------------------------------------------
__global__ void k_count(const int* __restrict__ dst, int E, int* __restrict__ deg)
{
    int e = blockIdx.x * 256 + threadIdx.x;
    if (e < E) atomicAdd(&deg[dst[e]], 1);
}

__global__ __launch_bounds__(1024) void k_scan(const int* __restrict__ deg, int n,
                                               int* __restrict__ off, int* __restrict__ cursor)
{
    __shared__ int wsum[16];
    __shared__ int carry_sh;
    int tid = threadIdx.x, lane = tid & 63, wid = tid >> 6;
    if (tid == 0) { carry_sh = 0; off[0] = 0; }
    __syncthreads();
    for (int base = 0; base < n; base += 1024) {
        int i = base + tid;
        int v = (i < n) ? deg[i] : 0;
        int s = v;
#pragma unroll
        for (int o = 1; o < 64; o <<= 1) {
            int t = __shfl_up(s, o);
            if (lane >= o) s += t;
        }
        if (lane == 63) wsum[wid] = s;
        __syncthreads();
        if (wid == 0) {
            int t = (lane < 16) ? wsum[lane] : 0;
#pragma unroll
            for (int o = 1; o < 16; o <<= 1) {
                int u = __shfl_up(t, o);
                if (lane >= o) t += u;
            }
            if (lane < 16) wsum[lane] = t;   // inclusive over wave sums
        }
        __syncthreads();
        int carry = carry_sh;
        int wexcl = (wid == 0) ? 0 : wsum[wid - 1];
        int incl = carry + wexcl + s;
        if (i < n) { off[i + 1] = incl; cursor[i] = incl - v; }
        __syncthreads();
        if (tid == 0) carry_sh = carry + wsum[15];
        __syncthreads();
    }
}

__global__ void k_scatter(const int* __restrict__ dst, int E,
                          int* __restrict__ cursor, int* __restrict__ eid)
{
    int e = blockIdx.x * 256 + threadIdx.x;
    if (e < E) {
        int p = atomicAdd(&cursor[dst[e]], 1);
        eid[p] = e;
    }
}

// ---------------------------------------------------------------------------
// Layer-1 aggregate in F=128 space: per (dst i, batch b) block.
// agg[b*ND1+i][h][c] = sum_e softmax_w(e,h) * xg[src_e][c]   (bf16 out)
// 256 threads: thread owns channel c=tid&127 for 6 heads (h=(tid>>7)+2q).
// ---------------------------------------------------------------------------
#define CHUNK 64
__global__ __launch_bounds__(256) void k_agg1(const unsigned short* __restrict__ xg,
                                              const float* __restrict__ es,
                                              const float* __restrict__ ed,
                                              const int* __restrict__ res1,
                                              const int* __restrict__ off,
                                              const int* __restrict__ eid,
                                              const int* __restrict__ src1,
                                              unsigned short* __restrict__ agg)
{
    const int i = blockIdx.x;   // dst node
    const int b = blockIdx.y;   // batch
    const int tid = threadIdx.x;

    __shared__ float a_ch[CHUNK][HEADS];
    __shared__ int   src_ch[CHUNK];
    __shared__ float m_sh[HEADS], den_sh[HEADS], fac_sh[HEADS], ed_sh[HEADS];

    int beg = off[i], end = off[i + 1];
    int deg = end - beg;

    if (tid < HEADS) {
        m_sh[tid] = -INFINITY;
        den_sh[tid] = 0.f;
        ed_sh[tid] = ed[((size_t)(b * NS1 + res1[i])) * HEADS + tid];
    }
    float acc[6] = {0.f, 0.f, 0.f, 0.f, 0.f, 0.f};
    int hq[6];
#pragma unroll
    for (int q = 0; q < 6; ++q) hq[q] = 2 * q + (tid >> 7);
    const int cch = tid & 127;
    __syncthreads();

    for (int cbeg = 0; cbeg < deg; cbeg += CHUNK) {
        int cnt = min(CHUNK, deg - cbeg);
        if (tid < cnt) src_ch[tid] = src1[eid[beg + cbeg + tid]];
        __syncthreads();
        for (int idx = tid; idx < cnt * HEADS; idx += 256) {
            int e = idx / HEADS, h = idx - e * HEADS;
            float al = es[((size_t)(b * NS1 + src_ch[e])) * HEADS + h] + ed_sh[h];
            a_ch[e][h] = lrelu(al);
        }
        __syncthreads();
        if (tid < HEADS) {
            int h = tid;
            float m = m_sh[h];
            float nm = m;
            for (int e = 0; e < cnt; ++e) nm = fmaxf(nm, a_ch[e][h]);
            float fac = (m == -INFINITY) ? 0.f : __expf(m - nm);
            float d = den_sh[h] * fac;
            for (int e = 0; e < cnt; ++e) {
                float w = __expf(a_ch[e][h] - nm);
                a_ch[e][h] = w;
                d += w;
            }
            m_sh[h] = nm; den_sh[h] = d; fac_sh[h] = fac;
        }
        __syncthreads();
#pragma unroll
        for (int q = 0; q < 6; ++q) acc[q] *= fac_sh[hq[q]];
        for (int e = 0; e < cnt; ++e) {
            float xv = bf2f(xg[((size_t)(b * NS1 + src_ch[e])) * F_IN + cch]);
#pragma unroll
            for (int q = 0; q < 6; ++q) {
                acc[q] += a_ch[e][hq[q]] * xv;
            }
        }
        __syncthreads();
    }

    const size_t rowbase = ((size_t)(b * ND1 + i)) * K1;
#pragma unroll
    for (int q = 0; q < 6; ++q) {
        agg[rowbase + tid + 256 * q] = f2bf(acc[q] / (den_sh[hq[q]] + 1e-16f));
    }
}

// ---------------------------------------------------------------------------
// Post-aggregation projection fused with bias+relu+dot(W2):
// s2[row] = sum_h sum_n relu( (agg[row,h]@W1_h)[n] + bias1[h*128+n] ) * W2[h*128+n]
// Block = 64 rows (4 waves x 16), loop over 12 heads, MFMA 16x16x32.
// ---------------------------------------------------------------------------
__global__ __launch_bounds__(256) void k_out1(const unsigned short* __restrict__ agg,
                                              const unsigned short* __restrict__ WT,
                                              const float* __restrict__ bias1,
                                              const float* __restrict__ W2,
                                              float* __restrict__ s2)
{
    const int tid = threadIdx.x;
    const int wave = tid >> 6, lane = tid & 63;
    const int l15 = lane & 15, l4 = lane >> 4;
    const int row0 = blockIdx.x * 64 + wave * 16;    // wave's 16-row tile

    float partial[4] = {0.f, 0.f, 0.f, 0.f};

    for (int h = 0; h < HEADS; ++h) {
        f32x4 acc[8];
#pragma unroll
        for (int c = 0; c < 8; ++c) acc[c] = f32x4{0, 0, 0, 0};
        const unsigned short* Ap = agg + (size_t)(row0 + l15) * K1 + h * CH + l4 * 8;
#pragma unroll
        for (int kk = 0; kk < 4; ++kk) {
            bf16x8 a = *reinterpret_cast<const bf16x8*>(Ap + kk * 32);
#pragma unroll
            for (int c = 0; c < 8; ++c) {
                bf16x8 bb = *reinterpret_cast<const bf16x8*>(
                    WT + (size_t)(h * CH + c * 16 + l15) * F_IN + kk * 32 + l4 * 8);
                acc[c] = __builtin_amdgcn_mfma_f32_16x16x32_bf16(a, bb, acc[c], 0, 0, 0);
            }
        }
#pragma unroll
        for (int c = 0; c < 8; ++c) {
            int n = h * CH + c * 16 + l15;
            float bi = bias1[n];
            float w2 = W2[n];
#pragma unroll
            for (int r = 0; r < 4; ++r) {
                float v = acc[c][r] + bi;
                v = v > 0.f ? v : 0.f;
                partial[r] += v * w2;
            }
        }
    }
    // reduce across the 16 lanes sharing each row (l15 group)
#pragma unroll
    for (int r = 0; r < 4; ++r) {
#pragma unroll
        for (int o = 1; o < 16; o <<= 1) partial[r] += __shfl_xor(partial[r], o);
    }
    if (l15 == 0) {
#pragma unroll
        for (int r = 0; r < 4; ++r) s2[row0 + l4 * 4 + r] = partial[r];
    }
}

// ---------------------------------------------------------------------------
// Layer-2 (heads=1, ch=1): one thread per (dst j, batch b).
// ---------------------------------------------------------------------------
__global__ void k_agg2(const float* __restrict__ s2,
                       const int* __restrict__ off,
                       const int* __restrict__ eid,
                       const int* __restrict__ src2,
                       const int* __restrict__ res2,
                       const float* __restrict__ asrc,
                       const float* __restrict__ adst,
                       const float* __restrict__ bias2,
                       float* __restrict__ out)
{
    int t = blockIdx.x * 256 + threadIdx.x;
    if (t >= 2 * ND2) return;
    int b = t / ND2, j = t - b * ND2;
    float a_s = asrc[0], a_d = adst[0];
    float ed = s2[(size_t)b * ND1 + res2[j]] * a_d;
    int beg = off[j], end = off[j + 1];
    float m = -INFINITY;
    for (int p = beg; p < end; ++p) {
        int s = src2[eid[p]];
        m = fmaxf(m, lrelu(s2[b * ND1 + s] * a_s + ed));
    }
    float den = 0.f, num = 0.f;
    for (int p = beg; p < end; ++p) {
        int s = src2[eid[p]];
        float v = s2[b * ND1 + s];
        float al = lrelu(v * a_s + ed);
        float w = __expf(al - m);
        den += w;
        num += w * v;
    }
    float o = (end > beg) ? num / (den + 1e-16f) : 0.f;
    out[(size_t)b * ND2 + j] = o + bias2[0];
}

// ---------------------------------------------------------------------------
extern "C" void kernel_launch(void* const* d_in, const int* in_sizes, int n_in,
                              void* d_out, int out_size, void* d_ws, size_t ws_size,
                              hipStream_t stream)
{
    const float* x        = (const float*)d_in[0];
    const int* n_id1      = (const int*)d_in[1];
    const int* res_n_id1  = (const int*)d_in[2];
    const int* src1       = (const int*)d_in[3];
    const int* dst1       = (const int*)d_in[4];
    const int* res_n_id2  = (const int*)d_in[5];
    const int* src2       = (const int*)d_in[6];
    const int* dst2       = (const int*)d_in[7];
    const float* W1       = (const float*)d_in[8];
    const float* att_src1 = (const float*)d_in[9];
    const float* att_dst1 = (const float*)d_in[10];
    const float* bias1    = (const float*)d_in[11];
    const float* W2       = (const float*)d_in[12];
    const float* att_src2 = (const float*)d_in[13];
    const float* att_dst2 = (const float*)d_in[14];
    const float* bias2    = (const float*)d_in[15];

    // workspace layout (16B aligned)
    unsigned short* xg   = (unsigned short*)d_ws;            // 4,096,000
    unsigned short* W1T  = xg + (size_t)2 * NS1 * F_IN;      //   196,608
    unsigned short* wswd = W1T + (size_t)K1 * F_IN;          //     4,096
    unsigned short* agg  = wswd + (size_t)32 * F_IN;         // 24,576,000
    float* es  = (float*)(agg + (size_t)2 * ND1 * K1);       //   384,000
    float* ed  = es + (size_t)2 * NS1 * HEADS;               //   384,000
    float* s2  = ed + (size_t)2 * NS1 * HEADS;               //    16,000
    int* deg1  = (int*)(s2 + (size_t)2 * ND1);               // 8000
    int* deg2  = deg1 + ND1;                                 // 4000
    int* off1  = deg2 + ND2;                                 // 8001
    int* off2  = off1 + (ND1 + 1);                           // 4001
    int* cur1  = off2 + (ND2 + 1);                           // 8000
    int* cur2  = cur1 + ND1;                                 // 4000
    int* eid1  = cur2 + ND2;                                 // 100000
    int* eid2  = eid1 + E1;                                  // 60000

    hipMemsetAsync(deg1, 0, (ND1 + ND2) * sizeof(int), stream);

    // prep
    k_convA<<<(2 * NS1 * (F_IN / 4) + 255) / 256, 256, 0, stream>>>(x, n_id1, xg);
    k_convB<<<(F_IN * K1 + 255) / 256, 256, 0, stream>>>(W1, W1T);
    k_ws<<<16, 256, 0, stream>>>(W1, att_src1, att_dst1, wswd);

    // scores for all 32000 rows
    k_escore<<<500, 256, 0, stream>>>(xg, wswd, es, ed);

    // CSR
    k_count<<<(E1 + 255) / 256, 256, 0, stream>>>(dst1, E1, deg1);
    k_scan<<<1, 1024, 0, stream>>>(deg1, ND1, off1, cur1);
    k_scatter<<<(E1 + 255) / 256, 256, 0, stream>>>(dst1, E1, cur1, eid1);

    k_count<<<(E2 + 255) / 256, 256, 0, stream>>>(dst2, E2, deg2);
    k_scan<<<1, 1024, 0, stream>>>(deg2, ND2, off2, cur2);
    k_scatter<<<(E2 + 255) / 256, 256, 0, stream>>>(dst2, E2, cur2, eid2);

    // layer-1 softmax-aggregate in F space
    k_agg1<<<dim3(ND1, B2), 256, 0, stream>>>(xg, es, ed, res_n_id1,
                                              off1, eid1, src1, agg);

    // projection + bias + relu + dot(W2) -> s2
    k_out1<<<(2 * ND1) / 64, 256, 0, stream>>>(agg, W1T, bias1, W2, s2);

    // layer-2
    k_agg2<<<(2 * ND2 + 255) / 256, 256, 0, stream>>>(s2, off2, eid2, src2,
                                                      res_n_id2, att_src2,
                                                      att_dst2, bias2,
                                                      (float*)d_out);
}